// Round 10
// baseline (650.075 us; speedup 1.0000x reference)
//
#include <hip/hip_runtime.h>
#include <hip/hip_bf16.h>
#include <math.h>

#define B_    4
#define L_    16384
#define DM    96
#define DI    96
#define NS    64
#define RK    6
#define KG_   4
#define CDIM  134   // RK + 2*NS

#define CL    128   // scan chunk length
#define NC    128   // chunks (CL*NC == L_)
#define NWARM 32    // warmup steps re-run from h=0 (decay ~e^-0.7/step -> e^-22)
#define STG   16    // LDS staging depth (steps)

typedef float f32x2 __attribute__((ext_vector_type(2)));
typedef float f32x4 __attribute__((ext_vector_type(4)));
typedef short bf16x8 __attribute__((ext_vector_type(8)));

#if defined(__has_builtin)
# if __has_builtin(__builtin_amdgcn_exp2f)
#  define EXP2F(x) __builtin_amdgcn_exp2f(x)
# else
#  define EXP2F(x) exp2f(x)
# endif
#else
# define EXP2F(x) exp2f(x)
#endif

__device__ __forceinline__ float gelu_f(float v) {
  return 0.5f * v * (1.0f + erff(v * 0.70710678118654752f));
}

__device__ __forceinline__ unsigned short f2bf(float v) {
  __hip_bfloat16 h = __float2bfloat16(v);
  return *reinterpret_cast<unsigned short*>(&h);
}

// ---------------- K1: fused in_proj GEMM + depthwise conv3 + gelu ---------
__global__ __launch_bounds__(256) void k_front(
    const float* __restrict__ x, const float* __restrict__ w,
    const float* __restrict__ cw,
    float* __restrict__ xxc, float* __restrict__ zg)
{
  __shared__ float sx[80][100];
  __shared__ float sw[96][100];   // W half; reused as product tile [80][100]
  const int tid = threadIdx.x;
  const int lt = blockIdx.x, cs = blockIdx.y, b = blockIdx.z;
  const int l0 = lt * 64;
  const int lbase = l0 - 1;

  for (int i = tid; i < 80 * 24; i += 256) {
    const int r = i / 24, q = i % 24;
    int l = lbase + r; l = l < 0 ? 0 : (l >= L_ ? L_ - 1 : l);
    const float4 v = reinterpret_cast<const float4*>(x + ((size_t)b * L_ + l) * DM)[q];
    *reinterpret_cast<float4*>(&sx[r][q * 4]) = v;
  }
  const float* wp = w + (size_t)cs * 96 * DM;
  for (int i = tid; i < 96 * 24; i += 256) {
    const int r = i / 24, q = i % 24;
    const float4 v = reinterpret_cast<const float4*>(wp + (size_t)r * DM)[q];
    *reinterpret_cast<float4*>(&sw[r][q * 4]) = v;
  }
  __syncthreads();

  const int rg = tid & 15, cg = tid >> 4;
  float acc[5][6];
#pragma unroll
  for (int i = 0; i < 5; ++i)
#pragma unroll
    for (int jj = 0; jj < 6; ++jj) acc[i][jj] = 0.f;

  for (int d0 = 0; d0 < 96; d0 += 4) {
    float4 a[5], wv[6];
#pragma unroll
    for (int i = 0; i < 5; ++i)
      a[i] = *reinterpret_cast<const float4*>(&sx[rg + 16 * i][d0]);
#pragma unroll
    for (int jj = 0; jj < 6; ++jj)
      wv[jj] = *reinterpret_cast<const float4*>(&sw[cg + 16 * jj][d0]);
#pragma unroll
    for (int i = 0; i < 5; ++i)
#pragma unroll
      for (int jj = 0; jj < 6; ++jj)
        acc[i][jj] += a[i].x * wv[jj].x + a[i].y * wv[jj].y
                    + a[i].z * wv[jj].z + a[i].w * wv[jj].w;
  }

  __syncthreads();
  float* sprod = &sw[0][0];  // reuse as [80][100]
#pragma unroll
  for (int i = 0; i < 5; ++i)
#pragma unroll
    for (int jj = 0; jj < 6; ++jj)
      sprod[(rg + 16 * i) * 100 + (cg + 16 * jj)] = acc[i][jj];
  __syncthreads();

  if (cs == 0) {
    float* op = xxc + ((size_t)b * L_ + l0) * DI;
    for (int i = tid; i < 64 * 24; i += 256) {
      const int ro = i / 24, q = i % 24;
      const int lo = l0 + ro;
      const float4 xm4 = *reinterpret_cast<const float4*>(&sprod[ro * 100 + q * 4]);
      const float4 x04 = *reinterpret_cast<const float4*>(&sprod[(ro + 1) * 100 + q * 4]);
      const float4 xq4 = *reinterpret_cast<const float4*>(&sprod[(ro + 2) * 100 + q * 4]);
      const float mzero = (lo > 0) ? 1.f : 0.f;
      const float qzero = (lo < L_ - 1) ? 1.f : 0.f;
      float4 o;
      {
        const int d0 = q * 4;
        const float* c = cw + d0 * 3;
        o.x = gelu_f(c[0] * xm4.x * mzero + c[1]  * x04.x + c[2]  * xq4.x * qzero);
        o.y = gelu_f(c[3] * xm4.y * mzero + c[4]  * x04.y + c[5]  * xq4.y * qzero);
        o.z = gelu_f(c[6] * xm4.z * mzero + c[7]  * x04.z + c[8]  * xq4.z * qzero);
        o.w = gelu_f(c[9] * xm4.w * mzero + c[10] * x04.w + c[11] * xq4.w * qzero);
      }
      reinterpret_cast<float4*>(op + (size_t)ro * DI)[q] = o;
    }
  } else {
    float* op = zg + ((size_t)b * L_ + l0) * DI;
    for (int i = tid; i < 64 * 24; i += 256) {
      const int ro = i / 24, q = i % 24;
      const float4 v = *reinterpret_cast<const float4*>(&sprod[(ro + 1) * 100 + q * 4]);
      float4 o;
      o.x = gelu_f(v.x); o.y = gelu_f(v.y); o.z = gelu_f(v.z); o.w = gelu_f(v.w);
      reinterpret_cast<float4*>(op + (size_t)ro * DI)[q] = o;
    }
  }
}

// ---------------- K3: x_proj + dt_proj + softplus via bf16 MFMA ----------
__global__ __launch_bounds__(256) void k_xproj(
    const float* __restrict__ xxc, const float* __restrict__ xpw,
    const float* __restrict__ dtw,
    __hip_bfloat16* __restrict__ delta, __hip_bfloat16* __restrict__ Bs,
    __hip_bfloat16* __restrict__ Cs)
{
  __shared__ __align__(16) unsigned short sxb[64][104];  // x tile bf16 (pad 104)
  __shared__ __align__(16) unsigned short swb[144 * 104];// W bf16 [144][104]; reused post-MFMA
  __shared__ __align__(16) float sdtw[576];              // dt_projs_w[k] (96x6)
  const int tid = threadIdx.x;
  const int lt = blockIdx.x, kdir = blockIdx.y, b = blockIdx.z;
  const int l0 = lt * 64;
  const bool rev = (kdir & 1) != 0;

  for (int i = tid; i < 576; i += 256) sdtw[i] = dtw[(size_t)kdir * 576 + i];

  for (int i = tid; i < 64 * 24; i += 256) {
    const int r = i / 24, q = i % 24;
    const int l = l0 + r;
    const int p = rev ? (L_ - 1 - l) : l;
    const float4 v = reinterpret_cast<const float4*>(xxc + ((size_t)b * L_ + p) * DI)[q];
    ushort4 u;
    u.x = f2bf(v.x); u.y = f2bf(v.y); u.z = f2bf(v.z); u.w = f2bf(v.w);
    *reinterpret_cast<ushort4*>(&sxb[r][q * 4]) = u;
  }
  const float* wp = xpw + (size_t)kdir * CDIM * DI;
  for (int i = tid; i < 144 * 24; i += 256) {
    const int r = i / 24, q = i % 24;
    float4 v = make_float4(0.f, 0.f, 0.f, 0.f);
    if (r < CDIM) v = reinterpret_cast<const float4*>(wp + (size_t)r * DI)[q];
    ushort4 u;
    u.x = f2bf(v.x); u.y = f2bf(v.y); u.z = f2bf(v.z); u.w = f2bf(v.w);
    *reinterpret_cast<ushort4*>(&swb[r * 104 + q * 4]) = u;
  }
  __syncthreads();

  const int wv = tid >> 6, lane = tid & 63;
  const int m0 = wv * 16;
  const int lrow = lane & 15, lkg = lane >> 4;
  f32x4 acc[9];
#pragma unroll
  for (int n = 0; n < 9; ++n) acc[n] = (f32x4){0.f, 0.f, 0.f, 0.f};

#pragma unroll
  for (int kk = 0; kk < 3; ++kk) {
    const int kbase = kk * 32 + lkg * 8;
    const bf16x8 af = *reinterpret_cast<const bf16x8*>(&sxb[m0 + lrow][kbase]);
#pragma unroll
    for (int n = 0; n < 9; ++n) {
      const bf16x8 bfm = *reinterpret_cast<const bf16x8*>(&swb[(n * 16 + lrow) * 104 + kbase]);
      acc[n] = __builtin_amdgcn_mfma_f32_16x16x32_bf16(af, bfm, acc[n], 0, 0, 0);
    }
  }
  __syncthreads();

  unsigned short* soB = swb;               // [64][68] bf16
  unsigned short* soC = swb + 64 * 68;     // [64][68] bf16
  float* sdts = reinterpret_cast<float*>(swb + 2 * 64 * 68);  // [64][8] fp32

  {
    const int row = m0 + lkg * 4;
#pragma unroll
    for (int n = 0; n < 9; ++n) {
      const int c = n * 16 + lrow;
#pragma unroll
      for (int reg = 0; reg < 4; ++reg) {
        const float v = acc[n][reg];
        const int rr = row + reg;
        if (c < RK)            sdts[rr * 8 + c] = v;
        else if (c < RK + NS)  soB[rr * 68 + (c - RK)] = f2bf(v);
        else if (c < CDIM)     soC[rr * 68 + (c - RK - NS)] = f2bf(v);
      }
    }
  }
  __syncthreads();

  const size_t bk = (size_t)(b * KG_ + kdir);
  {
    unsigned short* bsg = reinterpret_cast<unsigned short*>(Bs);
    unsigned short* csg = reinterpret_cast<unsigned short*>(Cs);
    const size_t nbase = (bk * L_ + l0) * NS;
    for (int i = tid; i < 64 * 16; i += 256) {
      const int r = i >> 4, q = i & 15;
      const ushort4 vb = *reinterpret_cast<const ushort4*>(&soB[r * 68 + q * 4]);
      const ushort4 vc = *reinterpret_cast<const ushort4*>(&soC[r * 68 + q * 4]);
      *reinterpret_cast<ushort4*>(bsg + nbase + (size_t)r * NS + q * 4) = vb;
      *reinterpret_cast<ushort4*>(csg + nbase + (size_t)r * NS + q * 4) = vc;
    }
  }
  {
    unsigned short* dg = reinterpret_cast<unsigned short*>(delta);
    const size_t dbase = (bk * L_ + l0) * DI;
    for (int i = tid; i < 64 * 24; i += 256) {
      const int r = i / 24, q = i - r * 24;
      const int dc0 = q * 4;
      ushort4 u;
      float o[4];
#pragma unroll
      for (int e = 0; e < 4; ++e) {
        const int dc = dc0 + e;
        float s = 0.f;
#pragma unroll
        for (int rr6 = 0; rr6 < RK; ++rr6)
          s += sdts[r * 8 + rr6] * sdtw[dc * RK + rr6];
        o[e] = (s > 20.f) ? s : log1pf(__expf(s));
      }
      u.x = f2bf(o[0]); u.y = f2bf(o[1]); u.z = f2bf(o[2]); u.w = f2bf(o[3]);
      *reinterpret_cast<ushort4*>(dg + dbase + (size_t)r * DI + dc0) = u;
    }
  }
}

// ---------------- K4: chunked selective scan, occupancy-optimized ---------
// 384 threads: d = tid>>2 (0..95), j = tid&3 -> 16 states each (8x f32x2,
// compiler math — known-correct scalarized form). LDS 26.6KB -> 5 blocks/CU
// (30 waves vs 24 at 768-thr). CL=128 so the grid (2048 blocks) fills them.
// D*u folded into s_y at staging (R8-proven); j==0 thread RMWs s_y.
__global__ __launch_bounds__(384, 8) void k_scan(
    const float* __restrict__ xxc,
    const __hip_bfloat16* __restrict__ delta,
    const __hip_bfloat16* __restrict__ Bs,
    const __hip_bfloat16* __restrict__ Cs,
    const float* __restrict__ A_logs, const float* __restrict__ Ds,
    float* __restrict__ ysum)
{
  __shared__ __align__(16) float s_du[STG][192];  // interleaved (delta, delta*u)
  __shared__ __align__(16) float s_B[STG][64];
  __shared__ __align__(16) float s_C[STG][64];
  __shared__ __align__(16) float s_y[STG][96];
  const int tid = threadIdx.x;
  const int ci = blockIdx.x, k = blockIdx.y, b = blockIdx.z;
  const int d = tid >> 2, j = tid & 3;
  const int jn = j * 16;
  const bool rev = (k & 1) != 0;
  const float LOG2E = 1.4426950408889634f;

  const int r96 = tid / 96;          // 0..3
  const int c96 = tid - r96 * 96;    // 0..95
  const int r64 = tid >> 6;          // 0..5
  const int c64 = tid & 63;

  f32x2 a2[8], h[8];
#pragma unroll
  for (int p = 0; p < 8; ++p) {
    const int n = jn + 2 * p;
    a2[p].x = -__expf(A_logs[((size_t)(k * DI + d)) * NS + n])     * LOG2E;
    a2[p].y = -__expf(A_logs[((size_t)(k * DI + d)) * NS + n + 1]) * LOG2E;
    h[p].x = 0.f; h[p].y = 0.f;
  }
  const float Dc = Ds[k * DI + c96];

  const int emit0 = ci * CL;
  const int lstart = (emit0 - NWARM > 0) ? (emit0 - NWARM) : 0;
  const int lend = emit0 + CL;
  const size_t bk = (size_t)(b * KG_ + k);

  for (int s = lstart; s < lend; s += STG) {
    __syncthreads();   // protect LDS overwrite vs previous compute/flush
    {
      const size_t dbase = (bk * L_ + s) * DI;
      const int pbase = rev ? (L_ - 1 - s) : s;
      const int psgn  = rev ? -1 : 1;
      const float* ubase = xxc + ((size_t)b * L_ + pbase) * DI + c96;
#pragma unroll
      for (int it = 0; it < 4; ++it) {
        const int t = r96 + 4 * it;
        const float dl = __bfloat162float(delta[dbase + (size_t)t * DI + c96]);
        const float uu = ubase[(ptrdiff_t)psgn * t * DI];
        f32x2 v; v.x = dl; v.y = dl * uu;
        *(f32x2*)&s_du[t][2 * c96] = v;
        s_y[t][c96] = Dc * uu;
      }
      const size_t nbase = (bk * L_ + s) * NS;
#pragma unroll
      for (int it = 0; it < 3; ++it) {
        const int t = r64 + 6 * it;
        if (t < STG) {
          s_B[t][c64] = __bfloat162float(Bs[nbase + (size_t)t * NS + c64]);
          s_C[t][c64] = __bfloat162float(Cs[nbase + (size_t)t * NS + c64]);
        }
      }
    }
    __syncthreads();
    const bool emit = (s >= emit0);
#pragma unroll 4
    for (int t = 0; t < STG; ++t) {
      const f32x2 du = *(const f32x2*)&s_du[t][2 * d];
      const float dlt = du.x, bu = du.y;
      const f32x2 dlt2 = {dlt, dlt};
      const f32x2 bu2 = {bu, bu};
      f32x4 Bq[4], Cq[4];
#pragma unroll
      for (int qq = 0; qq < 4; ++qq) {
        Bq[qq] = *(const f32x4*)&s_B[t][jn + 4 * qq];
        Cq[qq] = *(const f32x4*)&s_C[t][jn + 4 * qq];
      }
      f32x2 y2 = {0.f, 0.f};
#pragma unroll
      for (int p = 0; p < 8; ++p) {
        const f32x2 bpp = {Bq[p >> 1][(p & 1) * 2], Bq[p >> 1][(p & 1) * 2 + 1]};
        const f32x2 cpp = {Cq[p >> 1][(p & 1) * 2], Cq[p >> 1][(p & 1) * 2 + 1]};
        const f32x2 arg = dlt2 * a2[p];
        f32x2 e;
        e.x = EXP2F(arg.x);
        e.y = EXP2F(arg.y);
        h[p] = e * h[p] + bu2 * bpp;
        y2 += h[p] * cpp;
      }
      float y = y2.x + y2.y;
      y += __shfl_xor(y, 1);
      y += __shfl_xor(y, 2);
      if (emit && j == 0) s_y[t][d] += y;   // single writer per (t,d)
    }
    if (emit) {
      __syncthreads();   // s_y complete
      const int pbase = rev ? (L_ - 1 - s) : s;
      const int psgn  = rev ? -1 : 1;
      float* ybase = ysum + ((size_t)b * L_ + pbase) * DI + c96;
#pragma unroll
      for (int it = 0; it < 4; ++it) {
        const int t = r96 + 4 * it;
        atomicAdd(ybase + (ptrdiff_t)psgn * t * DI, s_y[t][c96]);
      }
    }
  }
}

// ---------------- K5: out = (ysum .* zg) @ Wout^T via bf16 MFMA ----------
__global__ __launch_bounds__(256) void k_out(
    const float* __restrict__ ysum, const float* __restrict__ zg,
    const float* __restrict__ wout, float* __restrict__ out)
{
  __shared__ __align__(16) char smem[64 * 104 * 2 + 96 * 104 * 2];
  unsigned short* sab = reinterpret_cast<unsigned short*>(smem);             // [64][104]
  unsigned short* swb = reinterpret_cast<unsigned short*>(smem + 64*104*2);  // [96][104]
  const int tid = threadIdx.x;
  const int lt = blockIdx.x, b = blockIdx.y;
  const int l0 = lt * 64;
  const size_t rbase = ((size_t)b * L_ + l0) * DI;

  for (int i = tid; i < 64 * 24; i += 256) {
    const int r = i / 24, q = i % 24;
    float4 av = reinterpret_cast<const float4*>(ysum + rbase + (size_t)r * DI)[q];
    const float4 zv = reinterpret_cast<const float4*>(zg + rbase + (size_t)r * DI)[q];
    ushort4 u;
    u.x = f2bf(av.x * zv.x); u.y = f2bf(av.y * zv.y);
    u.z = f2bf(av.z * zv.z); u.w = f2bf(av.w * zv.w);
    *reinterpret_cast<ushort4*>(&sab[r * 104 + q * 4]) = u;
  }
  for (int i = tid; i < 96 * 24; i += 256) {
    const int r = i / 24, q = i % 24;
    const float4 v = reinterpret_cast<const float4*>(wout + (size_t)r * DM)[q];
    ushort4 u;
    u.x = f2bf(v.x); u.y = f2bf(v.y); u.z = f2bf(v.z); u.w = f2bf(v.w);
    *reinterpret_cast<ushort4*>(&swb[r * 104 + q * 4]) = u;
  }
  __syncthreads();

  const int wv = tid >> 6, lane = tid & 63;
  const int m0 = wv * 16;
  const int lrow = lane & 15, lkg = lane >> 4;
  f32x4 acc[6];
#pragma unroll
  for (int n = 0; n < 6; ++n) acc[n] = (f32x4){0.f, 0.f, 0.f, 0.f};

#pragma unroll
  for (int kk = 0; kk < 3; ++kk) {
    const int kbase = kk * 32 + lkg * 8;
    const bf16x8 af = *reinterpret_cast<const bf16x8*>(&sab[(m0 + lrow) * 104 + kbase]);
#pragma unroll
    for (int n = 0; n < 6; ++n) {
      const bf16x8 bfm = *reinterpret_cast<const bf16x8*>(&swb[(n * 16 + lrow) * 104 + kbase]);
      acc[n] = __builtin_amdgcn_mfma_f32_16x16x32_bf16(af, bfm, acc[n], 0, 0, 0);
    }
  }
  __syncthreads();

  float* sout = reinterpret_cast<float*>(smem);  // [64][100] overlay
  {
    const int row = m0 + lkg * 4;
#pragma unroll
    for (int n = 0; n < 6; ++n) {
      const int c = n * 16 + lrow;
#pragma unroll
      for (int reg = 0; reg < 4; ++reg)
        sout[(row + reg) * 100 + c] = acc[n][reg];
    }
  }
  __syncthreads();

  float* op = out + ((size_t)b * L_ + l0) * DM;
  for (int i = tid; i < 64 * 24; i += 256) {
    const int r = i / 24, q = i % 24;
    const float4 v = *reinterpret_cast<const float4*>(&sout[r * 100 + q * 4]);
    reinterpret_cast<float4*>(op + (size_t)r * DM)[q] = v;
  }
}

extern "C" void kernel_launch(void* const* d_in, const int* in_sizes, int n_in,
                              void* d_out, int out_size, void* d_ws, size_t ws_size,
                              hipStream_t stream)
{
  const float* x    = (const float*)d_in[0];
  const float* ipw  = (const float*)d_in[1];
  const float* cw   = (const float*)d_in[2];
  const float* xpw  = (const float*)d_in[3];
  const float* dtw  = (const float*)d_in[4];
  const float* opw  = (const float*)d_in[5];
  const float* alog = (const float*)d_in[6];
  const float* dsv  = (const float*)d_in[7];
  float* out = (float*)d_out;
  char* ws = (char*)d_ws;

  const size_t SZ_XZ  = (size_t)B_ * L_ * 192 * 4;      // region reserved (delta lives here)
  const size_t SZ_F   = (size_t)B_ * L_ * DI * 4;       // 25,165,824
  const size_t SZ_NBF = (size_t)B_ * KG_ * L_ * NS * 2; // 33,554,432

  __hip_bfloat16* dlt  = (__hip_bfloat16*)ws;
  float* xxc           = (float*)(ws + SZ_XZ);
  float* zgp           = (float*)(ws + SZ_XZ + SZ_F);
  __hip_bfloat16* Bsp  = (__hip_bfloat16*)(ws + SZ_XZ + 2 * SZ_F);
  __hip_bfloat16* Csp  = (__hip_bfloat16*)(ws + SZ_XZ + 2 * SZ_F + SZ_NBF);
  float* ysum          = (float*)(ws + SZ_XZ + 2 * SZ_F + 2 * SZ_NBF);

  hipMemsetAsync(ysum, 0, SZ_F, stream);
  k_front  <<<dim3(L_ / 64, 2, B_),   256, 0, stream>>>(x, ipw, cw, xxc, zgp);
  k_xproj  <<<dim3(L_ / 64, KG_, B_), 256, 0, stream>>>(xxc, xpw, dtw, dlt, Bsp, Csp);
  k_scan   <<<dim3(NC, KG_, B_),      384, 0, stream>>>(xxc, dlt, Bsp, Csp, alog, dsv, ysum);
  k_out    <<<dim3(L_ / 64, B_),      256, 0, stream>>>(ysum, zgp, opw, out);
}

// Round 11
// 649.775 us; speedup vs baseline: 1.0005x; 1.0005x over previous
//
#include <hip/hip_runtime.h>
#include <hip/hip_bf16.h>
#include <math.h>

#define B_    4
#define L_    16384
#define DM    96
#define DI    96
#define NS    64
#define RK    6
#define KG_   4
#define CDIM  134   // RK + 2*NS

#define CL    512   // scan chunk length (L2-locality sweet spot; CL=128 regressed)
#define NC    32    // chunks (CL*NC == L_)
#define NWARM 64    // warmup steps re-run from h=0 (decay ~e^-0.7/step -> e^-45)
#define STG   32    // LDS staging depth (steps), single-buffered (R6-proven)

typedef float f32x2 __attribute__((ext_vector_type(2)));
typedef float f32x4 __attribute__((ext_vector_type(4)));
typedef short bf16x8 __attribute__((ext_vector_type(8)));

#if defined(__has_builtin)
# if __has_builtin(__builtin_amdgcn_exp2f)
#  define EXP2F(x) __builtin_amdgcn_exp2f(x)
# else
#  define EXP2F(x) exp2f(x)
# endif
#else
# define EXP2F(x) exp2f(x)
#endif

__device__ __forceinline__ float gelu_f(float v) {
  return 0.5f * v * (1.0f + erff(v * 0.70710678118654752f));
}

__device__ __forceinline__ unsigned short f2bf(float v) {
  __hip_bfloat16 h = __float2bfloat16(v);
  return *reinterpret_cast<unsigned short*>(&h);
}

// ---------------- K1: fused in_proj GEMM + depthwise conv3 + gelu ---------
__global__ __launch_bounds__(256) void k_front(
    const float* __restrict__ x, const float* __restrict__ w,
    const float* __restrict__ cw,
    float* __restrict__ xxc, float* __restrict__ zg)
{
  __shared__ float sx[80][100];
  __shared__ float sw[96][100];   // W half; reused as product tile [80][100]
  const int tid = threadIdx.x;
  const int lt = blockIdx.x, cs = blockIdx.y, b = blockIdx.z;
  const int l0 = lt * 64;
  const int lbase = l0 - 1;

  for (int i = tid; i < 80 * 24; i += 256) {
    const int r = i / 24, q = i % 24;
    int l = lbase + r; l = l < 0 ? 0 : (l >= L_ ? L_ - 1 : l);
    const float4 v = reinterpret_cast<const float4*>(x + ((size_t)b * L_ + l) * DM)[q];
    *reinterpret_cast<float4*>(&sx[r][q * 4]) = v;
  }
  const float* wp = w + (size_t)cs * 96 * DM;
  for (int i = tid; i < 96 * 24; i += 256) {
    const int r = i / 24, q = i % 24;
    const float4 v = reinterpret_cast<const float4*>(wp + (size_t)r * DM)[q];
    *reinterpret_cast<float4*>(&sw[r][q * 4]) = v;
  }
  __syncthreads();

  const int rg = tid & 15, cg = tid >> 4;
  float acc[5][6];
#pragma unroll
  for (int i = 0; i < 5; ++i)
#pragma unroll
    for (int jj = 0; jj < 6; ++jj) acc[i][jj] = 0.f;

  for (int d0 = 0; d0 < 96; d0 += 4) {
    float4 a[5], wv[6];
#pragma unroll
    for (int i = 0; i < 5; ++i)
      a[i] = *reinterpret_cast<const float4*>(&sx[rg + 16 * i][d0]);
#pragma unroll
    for (int jj = 0; jj < 6; ++jj)
      wv[jj] = *reinterpret_cast<const float4*>(&sw[cg + 16 * jj][d0]);
#pragma unroll
    for (int i = 0; i < 5; ++i)
#pragma unroll
      for (int jj = 0; jj < 6; ++jj)
        acc[i][jj] += a[i].x * wv[jj].x + a[i].y * wv[jj].y
                    + a[i].z * wv[jj].z + a[i].w * wv[jj].w;
  }

  __syncthreads();
  float* sprod = &sw[0][0];  // reuse as [80][100]
#pragma unroll
  for (int i = 0; i < 5; ++i)
#pragma unroll
    for (int jj = 0; jj < 6; ++jj)
      sprod[(rg + 16 * i) * 100 + (cg + 16 * jj)] = acc[i][jj];
  __syncthreads();

  if (cs == 0) {
    float* op = xxc + ((size_t)b * L_ + l0) * DI;
    for (int i = tid; i < 64 * 24; i += 256) {
      const int ro = i / 24, q = i % 24;
      const int lo = l0 + ro;
      const float4 xm4 = *reinterpret_cast<const float4*>(&sprod[ro * 100 + q * 4]);
      const float4 x04 = *reinterpret_cast<const float4*>(&sprod[(ro + 1) * 100 + q * 4]);
      const float4 xq4 = *reinterpret_cast<const float4*>(&sprod[(ro + 2) * 100 + q * 4]);
      const float mzero = (lo > 0) ? 1.f : 0.f;
      const float qzero = (lo < L_ - 1) ? 1.f : 0.f;
      float4 o;
      {
        const int d0 = q * 4;
        const float* c = cw + d0 * 3;
        o.x = gelu_f(c[0] * xm4.x * mzero + c[1]  * x04.x + c[2]  * xq4.x * qzero);
        o.y = gelu_f(c[3] * xm4.y * mzero + c[4]  * x04.y + c[5]  * xq4.y * qzero);
        o.z = gelu_f(c[6] * xm4.z * mzero + c[7]  * x04.z + c[8]  * xq4.z * qzero);
        o.w = gelu_f(c[9] * xm4.w * mzero + c[10] * x04.w + c[11] * xq4.w * qzero);
      }
      reinterpret_cast<float4*>(op + (size_t)ro * DI)[q] = o;
    }
  } else {
    float* op = zg + ((size_t)b * L_ + l0) * DI;
    for (int i = tid; i < 64 * 24; i += 256) {
      const int ro = i / 24, q = i % 24;
      const float4 v = *reinterpret_cast<const float4*>(&sprod[(ro + 1) * 100 + q * 4]);
      float4 o;
      o.x = gelu_f(v.x); o.y = gelu_f(v.y); o.z = gelu_f(v.z); o.w = gelu_f(v.w);
      reinterpret_cast<float4*>(op + (size_t)ro * DI)[q] = o;
    }
  }
}

// ---------------- K3: x_proj + dt_proj + softplus via bf16 MFMA ----------
__global__ __launch_bounds__(256) void k_xproj(
    const float* __restrict__ xxc, const float* __restrict__ xpw,
    const float* __restrict__ dtw,
    __hip_bfloat16* __restrict__ delta, __hip_bfloat16* __restrict__ Bs,
    __hip_bfloat16* __restrict__ Cs)
{
  __shared__ __align__(16) unsigned short sxb[64][104];  // x tile bf16 (pad 104)
  __shared__ __align__(16) unsigned short swb[144 * 104];// W bf16 [144][104]; reused post-MFMA
  __shared__ __align__(16) float sdtw[576];              // dt_projs_w[k] (96x6)
  const int tid = threadIdx.x;
  const int lt = blockIdx.x, kdir = blockIdx.y, b = blockIdx.z;
  const int l0 = lt * 64;
  const bool rev = (kdir & 1) != 0;

  for (int i = tid; i < 576; i += 256) sdtw[i] = dtw[(size_t)kdir * 576 + i];

  for (int i = tid; i < 64 * 24; i += 256) {
    const int r = i / 24, q = i % 24;
    const int l = l0 + r;
    const int p = rev ? (L_ - 1 - l) : l;
    const float4 v = reinterpret_cast<const float4*>(xxc + ((size_t)b * L_ + p) * DI)[q];
    ushort4 u;
    u.x = f2bf(v.x); u.y = f2bf(v.y); u.z = f2bf(v.z); u.w = f2bf(v.w);
    *reinterpret_cast<ushort4*>(&sxb[r][q * 4]) = u;
  }
  const float* wp = xpw + (size_t)kdir * CDIM * DI;
  for (int i = tid; i < 144 * 24; i += 256) {
    const int r = i / 24, q = i % 24;
    float4 v = make_float4(0.f, 0.f, 0.f, 0.f);
    if (r < CDIM) v = reinterpret_cast<const float4*>(wp + (size_t)r * DI)[q];
    ushort4 u;
    u.x = f2bf(v.x); u.y = f2bf(v.y); u.z = f2bf(v.z); u.w = f2bf(v.w);
    *reinterpret_cast<ushort4*>(&swb[r * 104 + q * 4]) = u;
  }
  __syncthreads();

  const int wv = tid >> 6, lane = tid & 63;
  const int m0 = wv * 16;
  const int lrow = lane & 15, lkg = lane >> 4;
  f32x4 acc[9];
#pragma unroll
  for (int n = 0; n < 9; ++n) acc[n] = (f32x4){0.f, 0.f, 0.f, 0.f};

#pragma unroll
  for (int kk = 0; kk < 3; ++kk) {
    const int kbase = kk * 32 + lkg * 8;
    const bf16x8 af = *reinterpret_cast<const bf16x8*>(&sxb[m0 + lrow][kbase]);
#pragma unroll
    for (int n = 0; n < 9; ++n) {
      const bf16x8 bfm = *reinterpret_cast<const bf16x8*>(&swb[(n * 16 + lrow) * 104 + kbase]);
      acc[n] = __builtin_amdgcn_mfma_f32_16x16x32_bf16(af, bfm, acc[n], 0, 0, 0);
    }
  }
  __syncthreads();

  unsigned short* soB = swb;               // [64][68] bf16
  unsigned short* soC = swb + 64 * 68;     // [64][68] bf16
  float* sdts = reinterpret_cast<float*>(swb + 2 * 64 * 68);  // [64][8] fp32

  {
    const int row = m0 + lkg * 4;
#pragma unroll
    for (int n = 0; n < 9; ++n) {
      const int c = n * 16 + lrow;
#pragma unroll
      for (int reg = 0; reg < 4; ++reg) {
        const float v = acc[n][reg];
        const int rr = row + reg;
        if (c < RK)            sdts[rr * 8 + c] = v;
        else if (c < RK + NS)  soB[rr * 68 + (c - RK)] = f2bf(v);
        else if (c < CDIM)     soC[rr * 68 + (c - RK - NS)] = f2bf(v);
      }
    }
  }
  __syncthreads();

  const size_t bk = (size_t)(b * KG_ + kdir);
  {
    unsigned short* bsg = reinterpret_cast<unsigned short*>(Bs);
    unsigned short* csg = reinterpret_cast<unsigned short*>(Cs);
    const size_t nbase = (bk * L_ + l0) * NS;
    for (int i = tid; i < 64 * 16; i += 256) {
      const int r = i >> 4, q = i & 15;
      const ushort4 vb = *reinterpret_cast<const ushort4*>(&soB[r * 68 + q * 4]);
      const ushort4 vc = *reinterpret_cast<const ushort4*>(&soC[r * 68 + q * 4]);
      *reinterpret_cast<ushort4*>(bsg + nbase + (size_t)r * NS + q * 4) = vb;
      *reinterpret_cast<ushort4*>(csg + nbase + (size_t)r * NS + q * 4) = vc;
    }
  }
  {
    unsigned short* dg = reinterpret_cast<unsigned short*>(delta);
    const size_t dbase = (bk * L_ + l0) * DI;
    for (int i = tid; i < 64 * 24; i += 256) {
      const int r = i / 24, q = i - r * 24;
      const int dc0 = q * 4;
      ushort4 u;
      float o[4];
#pragma unroll
      for (int e = 0; e < 4; ++e) {
        const int dc = dc0 + e;
        float s = 0.f;
#pragma unroll
        for (int rr6 = 0; rr6 < RK; ++rr6)
          s += sdts[r * 8 + rr6] * sdtw[dc * RK + rr6];
        o[e] = (s > 20.f) ? s : log1pf(__expf(s));
      }
      u.x = f2bf(o[0]); u.y = f2bf(o[1]); u.z = f2bf(o[2]); u.w = f2bf(o[3]);
      *reinterpret_cast<ushort4*>(dg + dbase + (size_t)r * DI + dc0) = u;
    }
  }
}

// ---------------- K4: chunked selective scan (R6 structure, scalar math) --
// 768 threads: d = tid>>3, j = tid&7 -> 8 states each. Hot loop in plain
// scalar fp32 (named regs, explicit fmaf) to eliminate ext_vector
// pack/unpack churn. D*u folded into s_y at staging; j==0 single-writer.
__global__ __launch_bounds__(768) void k_scan(
    const float* __restrict__ xxc,
    const __hip_bfloat16* __restrict__ delta,
    const __hip_bfloat16* __restrict__ Bs,
    const __hip_bfloat16* __restrict__ Cs,
    const float* __restrict__ A_logs, const float* __restrict__ Ds,
    float* __restrict__ ysum)
{
  __shared__ __align__(16) float s_du[STG][192];  // interleaved (delta, delta*u)
  __shared__ __align__(16) float s_B[STG][64];
  __shared__ __align__(16) float s_C[STG][64];
  __shared__ __align__(16) float s_y[STG][96];
  const int tid = threadIdx.x;
  const int ci = blockIdx.x, k = blockIdx.y, b = blockIdx.z;
  const int d = tid >> 3, j = tid & 7;
  const int jn = j * 8;
  const bool rev = (k & 1) != 0;
  const float LOG2E = 1.4426950408889634f;

  const int r96 = tid / 96;          // 0..7
  const int c96 = tid - r96 * 96;    // 0..95
  const int r64 = tid >> 6;          // 0..11
  const int c64 = tid & 63;

  float aA[8], h[8];
#pragma unroll
  for (int p = 0; p < 8; ++p) {
    aA[p] = -__expf(A_logs[((size_t)(k * DI + d)) * NS + jn + p]) * LOG2E;
    h[p] = 0.f;
  }
  const float Dc = Ds[k * DI + c96];

  const int emit0 = ci * CL;
  const int lstart = (emit0 - NWARM > 0) ? (emit0 - NWARM) : 0;
  const int lend = emit0 + CL;
  const size_t bk = (size_t)(b * KG_ + k);

  for (int s = lstart; s < lend; s += STG) {
    __syncthreads();   // protect LDS overwrite vs previous compute/flush
    const bool emit = (s >= emit0);
    {
      const size_t dbase = (bk * L_ + s) * DI;
      const int pbase = rev ? (L_ - 1 - s) : s;
      const int psgn  = rev ? -1 : 1;
      const float* ubase = xxc + ((size_t)b * L_ + pbase) * DI + c96;
#pragma unroll
      for (int it = 0; it < 4; ++it) {
        const int t = r96 + 8 * it;
        const float dl = __bfloat162float(delta[dbase + (size_t)t * DI + c96]);
        const float uu = ubase[(ptrdiff_t)psgn * t * DI];
        f32x2 v; v.x = dl; v.y = dl * uu;
        *(f32x2*)&s_du[t][2 * c96] = v;
        if (emit) s_y[t][c96] = Dc * uu;
      }
      const size_t nbase = (bk * L_ + s) * NS;
#pragma unroll
      for (int it = 0; it < 3; ++it) {
        const int t = r64 + 12 * it;
        if (t < STG) {
          s_B[t][c64] = __bfloat162float(Bs[nbase + (size_t)t * NS + c64]);
          s_C[t][c64] = __bfloat162float(Cs[nbase + (size_t)t * NS + c64]);
        }
      }
    }
    __syncthreads();
#pragma unroll 8
    for (int t = 0; t < STG; ++t) {
      const f32x2 du = *(const f32x2*)&s_du[t][2 * d];
      const float dlt = du.x, bu = du.y;
      const f32x4 Bv0 = *(const f32x4*)&s_B[t][jn];
      const f32x4 Bv1 = *(const f32x4*)&s_B[t][jn + 4];
      const f32x4 Cv0 = *(const f32x4*)&s_C[t][jn];
      const f32x4 Cv1 = *(const f32x4*)&s_C[t][jn + 4];
      float e[8];
#pragma unroll
      for (int p = 0; p < 8; ++p) e[p] = EXP2F(dlt * aA[p]);
      h[0] = fmaf(e[0], h[0], bu * Bv0.x);
      h[1] = fmaf(e[1], h[1], bu * Bv0.y);
      h[2] = fmaf(e[2], h[2], bu * Bv0.z);
      h[3] = fmaf(e[3], h[3], bu * Bv0.w);
      h[4] = fmaf(e[4], h[4], bu * Bv1.x);
      h[5] = fmaf(e[5], h[5], bu * Bv1.y);
      h[6] = fmaf(e[6], h[6], bu * Bv1.z);
      h[7] = fmaf(e[7], h[7], bu * Bv1.w);
      float ya = h[0] * Cv0.x;
      float yb = h[1] * Cv0.y;
      ya = fmaf(h[2], Cv0.z, ya);
      yb = fmaf(h[3], Cv0.w, yb);
      ya = fmaf(h[4], Cv1.x, ya);
      yb = fmaf(h[5], Cv1.y, yb);
      ya = fmaf(h[6], Cv1.z, ya);
      yb = fmaf(h[7], Cv1.w, yb);
      float y = ya + yb;
      y += __shfl_xor(y, 1);
      y += __shfl_xor(y, 2);
      y += __shfl_xor(y, 4);
      if (emit && j == 0) s_y[t][d] += y;   // single writer per (t,d)
    }
    if (emit) {
      __syncthreads();   // s_y complete (uniform branch)
      const int pbase = rev ? (L_ - 1 - s) : s;
      const int psgn  = rev ? -1 : 1;
      float* ybase = ysum + ((size_t)b * L_ + pbase) * DI + c96;
#pragma unroll
      for (int it = 0; it < 4; ++it) {
        const int t = r96 + 8 * it;
        atomicAdd(ybase + (ptrdiff_t)psgn * t * DI, s_y[t][c96]);
      }
    }
  }
}

// ---------------- K5: out = (ysum .* zg) @ Wout^T via bf16 MFMA ----------
__global__ __launch_bounds__(256) void k_out(
    const float* __restrict__ ysum, const float* __restrict__ zg,
    const float* __restrict__ wout, float* __restrict__ out)
{
  __shared__ __align__(16) char smem[64 * 104 * 2 + 96 * 104 * 2];
  unsigned short* sab = reinterpret_cast<unsigned short*>(smem);             // [64][104]
  unsigned short* swb = reinterpret_cast<unsigned short*>(smem + 64*104*2);  // [96][104]
  const int tid = threadIdx.x;
  const int lt = blockIdx.x, b = blockIdx.y;
  const int l0 = lt * 64;
  const size_t rbase = ((size_t)b * L_ + l0) * DI;

  for (int i = tid; i < 64 * 24; i += 256) {
    const int r = i / 24, q = i % 24;
    float4 av = reinterpret_cast<const float4*>(ysum + rbase + (size_t)r * DI)[q];
    const float4 zv = reinterpret_cast<const float4*>(zg + rbase + (size_t)r * DI)[q];
    ushort4 u;
    u.x = f2bf(av.x * zv.x); u.y = f2bf(av.y * zv.y);
    u.z = f2bf(av.z * zv.z); u.w = f2bf(av.w * zv.w);
    *reinterpret_cast<ushort4*>(&sab[r * 104 + q * 4]) = u;
  }
  for (int i = tid; i < 96 * 24; i += 256) {
    const int r = i / 24, q = i % 24;
    const float4 v = reinterpret_cast<const float4*>(wout + (size_t)r * DM)[q];
    ushort4 u;
    u.x = f2bf(v.x); u.y = f2bf(v.y); u.z = f2bf(v.z); u.w = f2bf(v.w);
    *reinterpret_cast<ushort4*>(&swb[r * 104 + q * 4]) = u;
  }
  __syncthreads();

  const int wv = tid >> 6, lane = tid & 63;
  const int m0 = wv * 16;
  const int lrow = lane & 15, lkg = lane >> 4;
  f32x4 acc[6];
#pragma unroll
  for (int n = 0; n < 6; ++n) acc[n] = (f32x4){0.f, 0.f, 0.f, 0.f};

#pragma unroll
  for (int kk = 0; kk < 3; ++kk) {
    const int kbase = kk * 32 + lkg * 8;
    const bf16x8 af = *reinterpret_cast<const bf16x8*>(&sab[(m0 + lrow) * 104 + kbase]);
#pragma unroll
    for (int n = 0; n < 6; ++n) {
      const bf16x8 bfm = *reinterpret_cast<const bf16x8*>(&swb[(n * 16 + lrow) * 104 + kbase]);
      acc[n] = __builtin_amdgcn_mfma_f32_16x16x32_bf16(af, bfm, acc[n], 0, 0, 0);
    }
  }
  __syncthreads();

  float* sout = reinterpret_cast<float*>(smem);  // [64][100] overlay
  {
    const int row = m0 + lkg * 4;
#pragma unroll
    for (int n = 0; n < 6; ++n) {
      const int c = n * 16 + lrow;
#pragma unroll
      for (int reg = 0; reg < 4; ++reg)
        sout[(row + reg) * 100 + c] = acc[n][reg];
    }
  }
  __syncthreads();

  float* op = out + ((size_t)b * L_ + l0) * DM;
  for (int i = tid; i < 64 * 24; i += 256) {
    const int r = i / 24, q = i % 24;
    const float4 v = *reinterpret_cast<const float4*>(&sout[r * 100 + q * 4]);
    reinterpret_cast<float4*>(op + (size_t)r * DM)[q] = v;
  }
}

extern "C" void kernel_launch(void* const* d_in, const int* in_sizes, int n_in,
                              void* d_out, int out_size, void* d_ws, size_t ws_size,
                              hipStream_t stream)
{
  const float* x    = (const float*)d_in[0];
  const float* ipw  = (const float*)d_in[1];
  const float* cw   = (const float*)d_in[2];
  const float* xpw  = (const float*)d_in[3];
  const float* dtw  = (const float*)d_in[4];
  const float* opw  = (const float*)d_in[5];
  const float* alog = (const float*)d_in[6];
  const float* dsv  = (const float*)d_in[7];
  float* out = (float*)d_out;
  char* ws = (char*)d_ws;

  const size_t SZ_XZ  = (size_t)B_ * L_ * 192 * 4;      // region reserved (delta lives here)
  const size_t SZ_F   = (size_t)B_ * L_ * DI * 4;       // 25,165,824
  const size_t SZ_NBF = (size_t)B_ * KG_ * L_ * NS * 2; // 33,554,432

  __hip_bfloat16* dlt  = (__hip_bfloat16*)ws;
  float* xxc           = (float*)(ws + SZ_XZ);
  float* zgp           = (float*)(ws + SZ_XZ + SZ_F);
  __hip_bfloat16* Bsp  = (__hip_bfloat16*)(ws + SZ_XZ + 2 * SZ_F);
  __hip_bfloat16* Csp  = (__hip_bfloat16*)(ws + SZ_XZ + 2 * SZ_F + SZ_NBF);
  float* ysum          = (float*)(ws + SZ_XZ + 2 * SZ_F + 2 * SZ_NBF);

  hipMemsetAsync(ysum, 0, SZ_F, stream);
  k_front  <<<dim3(L_ / 64, 2, B_),   256, 0, stream>>>(x, ipw, cw, xxc, zgp);
  k_xproj  <<<dim3(L_ / 64, KG_, B_), 256, 0, stream>>>(xxc, xpw, dtw, dlt, Bsp, Csp);
  k_scan   <<<dim3(NC, KG_, B_),      768, 0, stream>>>(xxc, dlt, Bsp, Csp, alog, dsv, ysum);
  k_out    <<<dim3(L_ / 64, B_),      256, 0, stream>>>(ysum, zgp, opw, out);
}

// Round 12
// 518.567 us; speedup vs baseline: 1.2536x; 1.2530x over previous
//
#include <hip/hip_runtime.h>
#include <hip/hip_bf16.h>
#include <math.h>

#define B_    4
#define L_    16384
#define DM    96
#define DI    96
#define NS    64
#define RK    6
#define KG_   4
#define CDIM  134   // RK + 2*NS

#define CL    512   // scan chunk length (L2-locality sweet spot; CL=128 regressed)
#define NC    32    // chunks (CL*NC == L_)
#define NWARM 64    // warmup steps re-run from h=0 (decay ~e^-0.7/step -> e^-45)
#define STG   32    // LDS staging depth (steps), single-buffered (R6-proven 354us)

typedef float f32x2 __attribute__((ext_vector_type(2)));
typedef float f32x4 __attribute__((ext_vector_type(4)));
typedef short bf16x8 __attribute__((ext_vector_type(8)));

#if defined(__has_builtin)
# if __has_builtin(__builtin_amdgcn_exp2f)
#  define EXP2F(x) __builtin_amdgcn_exp2f(x)
# else
#  define EXP2F(x) exp2f(x)
# endif
#else
# define EXP2F(x) exp2f(x)
#endif

__device__ __forceinline__ float gelu_f(float v) {
  return 0.5f * v * (1.0f + erff(v * 0.70710678118654752f));
}

__device__ __forceinline__ unsigned short f2bf(float v) {
  __hip_bfloat16 h = __float2bfloat16(v);
  return *reinterpret_cast<unsigned short*>(&h);
}

// ---------------- K1: fused in_proj GEMM + depthwise conv3 + gelu ---------
__global__ __launch_bounds__(256) void k_front(
    const float* __restrict__ x, const float* __restrict__ w,
    const float* __restrict__ cw,
    float* __restrict__ xxc, float* __restrict__ zg)
{
  __shared__ float sx[80][100];
  __shared__ float sw[96][100];   // W half; reused as product tile [80][100]
  const int tid = threadIdx.x;
  const int lt = blockIdx.x, cs = blockIdx.y, b = blockIdx.z;
  const int l0 = lt * 64;
  const int lbase = l0 - 1;

  for (int i = tid; i < 80 * 24; i += 256) {
    const int r = i / 24, q = i % 24;
    int l = lbase + r; l = l < 0 ? 0 : (l >= L_ ? L_ - 1 : l);
    const float4 v = reinterpret_cast<const float4*>(x + ((size_t)b * L_ + l) * DM)[q];
    *reinterpret_cast<float4*>(&sx[r][q * 4]) = v;
  }
  const float* wp = w + (size_t)cs * 96 * DM;
  for (int i = tid; i < 96 * 24; i += 256) {
    const int r = i / 24, q = i % 24;
    const float4 v = reinterpret_cast<const float4*>(wp + (size_t)r * DM)[q];
    *reinterpret_cast<float4*>(&sw[r][q * 4]) = v;
  }
  __syncthreads();

  const int rg = tid & 15, cg = tid >> 4;
  float acc[5][6];
#pragma unroll
  for (int i = 0; i < 5; ++i)
#pragma unroll
    for (int jj = 0; jj < 6; ++jj) acc[i][jj] = 0.f;

  for (int d0 = 0; d0 < 96; d0 += 4) {
    float4 a[5], wv[6];
#pragma unroll
    for (int i = 0; i < 5; ++i)
      a[i] = *reinterpret_cast<const float4*>(&sx[rg + 16 * i][d0]);
#pragma unroll
    for (int jj = 0; jj < 6; ++jj)
      wv[jj] = *reinterpret_cast<const float4*>(&sw[cg + 16 * jj][d0]);
#pragma unroll
    for (int i = 0; i < 5; ++i)
#pragma unroll
      for (int jj = 0; jj < 6; ++jj)
        acc[i][jj] += a[i].x * wv[jj].x + a[i].y * wv[jj].y
                    + a[i].z * wv[jj].z + a[i].w * wv[jj].w;
  }

  __syncthreads();
  float* sprod = &sw[0][0];  // reuse as [80][100]
#pragma unroll
  for (int i = 0; i < 5; ++i)
#pragma unroll
    for (int jj = 0; jj < 6; ++jj)
      sprod[(rg + 16 * i) * 100 + (cg + 16 * jj)] = acc[i][jj];
  __syncthreads();

  if (cs == 0) {
    float* op = xxc + ((size_t)b * L_ + l0) * DI;
    for (int i = tid; i < 64 * 24; i += 256) {
      const int ro = i / 24, q = i % 24;
      const int lo = l0 + ro;
      const float4 xm4 = *reinterpret_cast<const float4*>(&sprod[ro * 100 + q * 4]);
      const float4 x04 = *reinterpret_cast<const float4*>(&sprod[(ro + 1) * 100 + q * 4]);
      const float4 xq4 = *reinterpret_cast<const float4*>(&sprod[(ro + 2) * 100 + q * 4]);
      const float mzero = (lo > 0) ? 1.f : 0.f;
      const float qzero = (lo < L_ - 1) ? 1.f : 0.f;
      float4 o;
      {
        const int d0 = q * 4;
        const float* c = cw + d0 * 3;
        o.x = gelu_f(c[0] * xm4.x * mzero + c[1]  * x04.x + c[2]  * xq4.x * qzero);
        o.y = gelu_f(c[3] * xm4.y * mzero + c[4]  * x04.y + c[5]  * xq4.y * qzero);
        o.z = gelu_f(c[6] * xm4.z * mzero + c[7]  * x04.z + c[8]  * xq4.z * qzero);
        o.w = gelu_f(c[9] * xm4.w * mzero + c[10] * x04.w + c[11] * xq4.w * qzero);
      }
      reinterpret_cast<float4*>(op + (size_t)ro * DI)[q] = o;
    }
  } else {
    float* op = zg + ((size_t)b * L_ + l0) * DI;
    for (int i = tid; i < 64 * 24; i += 256) {
      const int ro = i / 24, q = i % 24;
      const float4 v = *reinterpret_cast<const float4*>(&sprod[(ro + 1) * 100 + q * 4]);
      float4 o;
      o.x = gelu_f(v.x); o.y = gelu_f(v.y); o.z = gelu_f(v.z); o.w = gelu_f(v.w);
      reinterpret_cast<float4*>(op + (size_t)ro * DI)[q] = o;
    }
  }
}

// ---------------- K3: x_proj + dt_proj + softplus via bf16 MFMA ----------
__global__ __launch_bounds__(256) void k_xproj(
    const float* __restrict__ xxc, const float* __restrict__ xpw,
    const float* __restrict__ dtw,
    __hip_bfloat16* __restrict__ delta, __hip_bfloat16* __restrict__ Bs,
    __hip_bfloat16* __restrict__ Cs)
{
  __shared__ __align__(16) unsigned short sxb[64][104];  // x tile bf16 (pad 104)
  __shared__ __align__(16) unsigned short swb[144 * 104];// W bf16 [144][104]; reused post-MFMA
  __shared__ __align__(16) float sdtw[576];              // dt_projs_w[k] (96x6)
  const int tid = threadIdx.x;
  const int lt = blockIdx.x, kdir = blockIdx.y, b = blockIdx.z;
  const int l0 = lt * 64;
  const bool rev = (kdir & 1) != 0;

  for (int i = tid; i < 576; i += 256) sdtw[i] = dtw[(size_t)kdir * 576 + i];

  for (int i = tid; i < 64 * 24; i += 256) {
    const int r = i / 24, q = i % 24;
    const int l = l0 + r;
    const int p = rev ? (L_ - 1 - l) : l;
    const float4 v = reinterpret_cast<const float4*>(xxc + ((size_t)b * L_ + p) * DI)[q];
    ushort4 u;
    u.x = f2bf(v.x); u.y = f2bf(v.y); u.z = f2bf(v.z); u.w = f2bf(v.w);
    *reinterpret_cast<ushort4*>(&sxb[r][q * 4]) = u;
  }
  const float* wp = xpw + (size_t)kdir * CDIM * DI;
  for (int i = tid; i < 144 * 24; i += 256) {
    const int r = i / 24, q = i % 24;
    float4 v = make_float4(0.f, 0.f, 0.f, 0.f);
    if (r < CDIM) v = reinterpret_cast<const float4*>(wp + (size_t)r * DI)[q];
    ushort4 u;
    u.x = f2bf(v.x); u.y = f2bf(v.y); u.z = f2bf(v.z); u.w = f2bf(v.w);
    *reinterpret_cast<ushort4*>(&swb[r * 104 + q * 4]) = u;
  }
  __syncthreads();

  const int wv = tid >> 6, lane = tid & 63;
  const int m0 = wv * 16;
  const int lrow = lane & 15, lkg = lane >> 4;
  f32x4 acc[9];
#pragma unroll
  for (int n = 0; n < 9; ++n) acc[n] = (f32x4){0.f, 0.f, 0.f, 0.f};

#pragma unroll
  for (int kk = 0; kk < 3; ++kk) {
    const int kbase = kk * 32 + lkg * 8;
    const bf16x8 af = *reinterpret_cast<const bf16x8*>(&sxb[m0 + lrow][kbase]);
#pragma unroll
    for (int n = 0; n < 9; ++n) {
      const bf16x8 bfm = *reinterpret_cast<const bf16x8*>(&swb[(n * 16 + lrow) * 104 + kbase]);
      acc[n] = __builtin_amdgcn_mfma_f32_16x16x32_bf16(af, bfm, acc[n], 0, 0, 0);
    }
  }
  __syncthreads();

  unsigned short* soB = swb;               // [64][68] bf16
  unsigned short* soC = swb + 64 * 68;     // [64][68] bf16
  float* sdts = reinterpret_cast<float*>(swb + 2 * 64 * 68);  // [64][8] fp32

  {
    const int row = m0 + lkg * 4;
#pragma unroll
    for (int n = 0; n < 9; ++n) {
      const int c = n * 16 + lrow;
#pragma unroll
      for (int reg = 0; reg < 4; ++reg) {
        const float v = acc[n][reg];
        const int rr = row + reg;
        if (c < RK)            sdts[rr * 8 + c] = v;
        else if (c < RK + NS)  soB[rr * 68 + (c - RK)] = f2bf(v);
        else if (c < CDIM)     soC[rr * 68 + (c - RK - NS)] = f2bf(v);
      }
    }
  }
  __syncthreads();

  const size_t bk = (size_t)(b * KG_ + kdir);
  {
    unsigned short* bsg = reinterpret_cast<unsigned short*>(Bs);
    unsigned short* csg = reinterpret_cast<unsigned short*>(Cs);
    const size_t nbase = (bk * L_ + l0) * NS;
    for (int i = tid; i < 64 * 16; i += 256) {
      const int r = i >> 4, q = i & 15;
      const ushort4 vb = *reinterpret_cast<const ushort4*>(&soB[r * 68 + q * 4]);
      const ushort4 vc = *reinterpret_cast<const ushort4*>(&soC[r * 68 + q * 4]);
      *reinterpret_cast<ushort4*>(bsg + nbase + (size_t)r * NS + q * 4) = vb;
      *reinterpret_cast<ushort4*>(csg + nbase + (size_t)r * NS + q * 4) = vc;
    }
  }
  {
    unsigned short* dg = reinterpret_cast<unsigned short*>(delta);
    const size_t dbase = (bk * L_ + l0) * DI;
    for (int i = tid; i < 64 * 24; i += 256) {
      const int r = i / 24, q = i - r * 24;
      const int dc0 = q * 4;
      ushort4 u;
      float o[4];
#pragma unroll
      for (int e = 0; e < 4; ++e) {
        const int dc = dc0 + e;
        float s = 0.f;
#pragma unroll
        for (int rr6 = 0; rr6 < RK; ++rr6)
          s += sdts[r * 8 + rr6] * sdtw[dc * RK + rr6];
        o[e] = (s > 20.f) ? s : log1pf(__expf(s));
      }
      u.x = f2bf(o[0]); u.y = f2bf(o[1]); u.z = f2bf(o[2]); u.w = f2bf(o[3]);
      *reinterpret_cast<ushort4*>(dg + dbase + (size_t)r * DI + dc0) = u;
    }
  }
}

// ---------------- K4: chunked selective scan (R6 code, verbatim) ----------
// The exact structure that measured 354us: 768 thr, STG=32 single-buffered,
// f32x2 compiler math, s_u array + fmaf at flush, unroll-8 hot loop.
__global__ __launch_bounds__(768) void k_scan(
    const float* __restrict__ xxc,
    const __hip_bfloat16* __restrict__ delta,
    const __hip_bfloat16* __restrict__ Bs,
    const __hip_bfloat16* __restrict__ Cs,
    const float* __restrict__ A_logs, const float* __restrict__ Ds,
    float* __restrict__ ysum)
{
  __shared__ __align__(16) float s_du[STG][192];  // interleaved (delta, delta*u)
  __shared__ __align__(16) float s_u[STG][96];
  __shared__ __align__(16) float s_B[STG][64];
  __shared__ __align__(16) float s_C[STG][64];
  __shared__ __align__(16) float s_y[STG][96];
  const int tid = threadIdx.x;
  const int ci = blockIdx.x, k = blockIdx.y, b = blockIdx.z;
  const int d = tid >> 3, j = tid & 7;
  const int jn = j * 8;
  const bool rev = (k & 1) != 0;
  const float LOG2E = 1.4426950408889634f;

  const int r96 = tid / 96;
  const int c96 = tid - r96 * 96;
  const int r64 = tid >> 6;
  const int c64 = tid & 63;

  f32x2 a2[4], h[4];
#pragma unroll
  for (int p = 0; p < 4; ++p) {
    const int n = jn + 2 * p;
    a2[p].x = -__expf(A_logs[((size_t)(k * DI + d)) * NS + n])     * LOG2E;
    a2[p].y = -__expf(A_logs[((size_t)(k * DI + d)) * NS + n + 1]) * LOG2E;
    h[p].x = 0.f; h[p].y = 0.f;
  }
  const float Dc = Ds[k * DI + c96];

  const int emit0 = ci * CL;
  const int lstart = (emit0 - NWARM > 0) ? (emit0 - NWARM) : 0;
  const int lend = emit0 + CL;
  const size_t bk = (size_t)(b * KG_ + k);

  for (int s = lstart; s < lend; s += STG) {
    __syncthreads();
    {
      const size_t dbase = (bk * L_ + s) * DI;
      const int pbase = rev ? (L_ - 1 - s) : s;
      const int psgn  = rev ? -1 : 1;
      const float* ubase = xxc + ((size_t)b * L_ + pbase) * DI + c96;
#pragma unroll
      for (int it = 0; it < 4; ++it) {
        const int t = r96 + 8 * it;
        const float dl = __bfloat162float(delta[dbase + (size_t)t * DI + c96]);
        const float uu = ubase[(ptrdiff_t)psgn * t * DI];
        f32x2 v; v.x = dl; v.y = dl * uu;
        *(f32x2*)&s_du[t][2 * c96] = v;
        s_u[t][c96] = uu;
      }
      const size_t nbase = (bk * L_ + s) * NS;
#pragma unroll
      for (int it = 0; it < 3; ++it) {
        const int t = r64 + 12 * it;
        if (t < STG) {
          s_B[t][c64] = __bfloat162float(Bs[nbase + (size_t)t * NS + c64]);
          s_C[t][c64] = __bfloat162float(Cs[nbase + (size_t)t * NS + c64]);
        }
      }
    }
    __syncthreads();
    const bool emit = (s >= emit0);
#pragma unroll 8
    for (int t = 0; t < STG; ++t) {
      const f32x2 du = *(const f32x2*)&s_du[t][2 * d];
      const float dlt = du.x, bu = du.y;
      const f32x2 dlt2 = {dlt, dlt};
      const f32x2 bu2 = {bu, bu};
      const f32x4 Bv0 = *(const f32x4*)&s_B[t][jn];
      const f32x4 Bv1 = *(const f32x4*)&s_B[t][jn + 4];
      const f32x4 Cv0 = *(const f32x4*)&s_C[t][jn];
      const f32x4 Cv1 = *(const f32x4*)&s_C[t][jn + 4];
      const f32x2 bp[4] = {{Bv0.x, Bv0.y}, {Bv0.z, Bv0.w},
                           {Bv1.x, Bv1.y}, {Bv1.z, Bv1.w}};
      const f32x2 cp[4] = {{Cv0.x, Cv0.y}, {Cv0.z, Cv0.w},
                           {Cv1.x, Cv1.y}, {Cv1.z, Cv1.w}};
      f32x2 y2 = {0.f, 0.f};
#pragma unroll
      for (int p = 0; p < 4; ++p) {
        const f32x2 arg = dlt2 * a2[p];
        f32x2 e;
        e.x = EXP2F(arg.x);
        e.y = EXP2F(arg.y);
        h[p] = e * h[p] + bu2 * bp[p];
        y2 += h[p] * cp[p];
      }
      float y = y2.x + y2.y;
      y += __shfl_xor(y, 1);
      y += __shfl_xor(y, 2);
      y += __shfl_xor(y, 4);
      if (emit && j == 0) s_y[t][d] = y;
    }
    if (emit) {
      __syncthreads();
      const int pbase = rev ? (L_ - 1 - s) : s;
      const int psgn  = rev ? -1 : 1;
      float* ybase = ysum + ((size_t)b * L_ + pbase) * DI + c96;
#pragma unroll
      for (int it = 0; it < 4; ++it) {
        const int t = r96 + 8 * it;
        atomicAdd(ybase + (ptrdiff_t)psgn * t * DI,
                  fmaf(Dc, s_u[t][c96], s_y[t][c96]));
      }
    }
  }
}

// ---------------- K5: out = (ysum .* zg) @ Wout^T via bf16 MFMA ----------
__global__ __launch_bounds__(256) void k_out(
    const float* __restrict__ ysum, const float* __restrict__ zg,
    const float* __restrict__ wout, float* __restrict__ out)
{
  __shared__ __align__(16) char smem[64 * 104 * 2 + 96 * 104 * 2];
  unsigned short* sab = reinterpret_cast<unsigned short*>(smem);             // [64][104]
  unsigned short* swb = reinterpret_cast<unsigned short*>(smem + 64*104*2);  // [96][104]
  const int tid = threadIdx.x;
  const int lt = blockIdx.x, b = blockIdx.y;
  const int l0 = lt * 64;
  const size_t rbase = ((size_t)b * L_ + l0) * DI;

  for (int i = tid; i < 64 * 24; i += 256) {
    const int r = i / 24, q = i % 24;
    float4 av = reinterpret_cast<const float4*>(ysum + rbase + (size_t)r * DI)[q];
    const float4 zv = reinterpret_cast<const float4*>(zg + rbase + (size_t)r * DI)[q];
    ushort4 u;
    u.x = f2bf(av.x * zv.x); u.y = f2bf(av.y * zv.y);
    u.z = f2bf(av.z * zv.z); u.w = f2bf(av.w * zv.w);
    *reinterpret_cast<ushort4*>(&sab[r * 104 + q * 4]) = u;
  }
  for (int i = tid; i < 96 * 24; i += 256) {
    const int r = i / 24, q = i % 24;
    const float4 v = reinterpret_cast<const float4*>(wout + (size_t)r * DM)[q];
    ushort4 u;
    u.x = f2bf(v.x); u.y = f2bf(v.y); u.z = f2bf(v.z); u.w = f2bf(v.w);
    *reinterpret_cast<ushort4*>(&swb[r * 104 + q * 4]) = u;
  }
  __syncthreads();

  const int wv = tid >> 6, lane = tid & 63;
  const int m0 = wv * 16;
  const int lrow = lane & 15, lkg = lane >> 4;
  f32x4 acc[6];
#pragma unroll
  for (int n = 0; n < 6; ++n) acc[n] = (f32x4){0.f, 0.f, 0.f, 0.f};

#pragma unroll
  for (int kk = 0; kk < 3; ++kk) {
    const int kbase = kk * 32 + lkg * 8;
    const bf16x8 af = *reinterpret_cast<const bf16x8*>(&sab[(m0 + lrow) * 104 + kbase]);
#pragma unroll
    for (int n = 0; n < 6; ++n) {
      const bf16x8 bfm = *reinterpret_cast<const bf16x8*>(&swb[(n * 16 + lrow) * 104 + kbase]);
      acc[n] = __builtin_amdgcn_mfma_f32_16x16x32_bf16(af, bfm, acc[n], 0, 0, 0);
    }
  }
  __syncthreads();

  float* sout = reinterpret_cast<float*>(smem);  // [64][100] overlay
  {
    const int row = m0 + lkg * 4;
#pragma unroll
    for (int n = 0; n < 6; ++n) {
      const int c = n * 16 + lrow;
#pragma unroll
      for (int reg = 0; reg < 4; ++reg)
        sout[(row + reg) * 100 + c] = acc[n][reg];
    }
  }
  __syncthreads();

  float* op = out + ((size_t)b * L_ + l0) * DM;
  for (int i = tid; i < 64 * 24; i += 256) {
    const int r = i / 24, q = i % 24;
    const float4 v = *reinterpret_cast<const float4*>(&sout[r * 100 + q * 4]);
    reinterpret_cast<float4*>(op + (size_t)r * DM)[q] = v;
  }
}

extern "C" void kernel_launch(void* const* d_in, const int* in_sizes, int n_in,
                              void* d_out, int out_size, void* d_ws, size_t ws_size,
                              hipStream_t stream)
{
  const float* x    = (const float*)d_in[0];
  const float* ipw  = (const float*)d_in[1];
  const float* cw   = (const float*)d_in[2];
  const float* xpw  = (const float*)d_in[3];
  const float* dtw  = (const float*)d_in[4];
  const float* opw  = (const float*)d_in[5];
  const float* alog = (const float*)d_in[6];
  const float* dsv  = (const float*)d_in[7];
  float* out = (float*)d_out;
  char* ws = (char*)d_ws;

  const size_t SZ_XZ  = (size_t)B_ * L_ * 192 * 4;      // region reserved (delta lives here)
  const size_t SZ_F   = (size_t)B_ * L_ * DI * 4;       // 25,165,824
  const size_t SZ_NBF = (size_t)B_ * KG_ * L_ * NS * 2; // 33,554,432

  __hip_bfloat16* dlt  = (__hip_bfloat16*)ws;
  float* xxc           = (float*)(ws + SZ_XZ);
  float* zgp           = (float*)(ws + SZ_XZ + SZ_F);
  __hip_bfloat16* Bsp  = (__hip_bfloat16*)(ws + SZ_XZ + 2 * SZ_F);
  __hip_bfloat16* Csp  = (__hip_bfloat16*)(ws + SZ_XZ + 2 * SZ_F + SZ_NBF);
  float* ysum          = (float*)(ws + SZ_XZ + 2 * SZ_F + 2 * SZ_NBF);

  hipMemsetAsync(ysum, 0, SZ_F, stream);
  k_front  <<<dim3(L_ / 64, 2, B_),   256, 0, stream>>>(x, ipw, cw, xxc, zgp);
  k_xproj  <<<dim3(L_ / 64, KG_, B_), 256, 0, stream>>>(xxc, xpw, dtw, dlt, Bsp, Csp);
  k_scan   <<<dim3(NC, KG_, B_),      768, 0, stream>>>(xxc, dlt, Bsp, Csp, alog, dsv, ysum);
  k_out    <<<dim3(L_ / 64, B_),      256, 0, stream>>>(ysum, zgp, opw, out);
}

// Round 13
// 479.017 us; speedup vs baseline: 1.3571x; 1.0826x over previous
//
#include <hip/hip_runtime.h>
#include <hip/hip_bf16.h>
#include <math.h>

#define B_    4
#define L_    16384
#define DM    96
#define DI    96
#define NS    64
#define RK    6
#define KG_   4
#define CDIM  134   // RK + 2*NS

#define CL    512   // scan chunk length (L2-locality sweet spot; CL=128 regressed)
#define NC    32    // chunks (CL*NC == L_)
#define NWARM 64    // warmup steps re-run from h=0 (decay ~e^-0.7/step -> e^-45)
#define STG   32    // LDS staging depth (steps), single-buffered (R6-proven 354us)

typedef float f32x2 __attribute__((ext_vector_type(2)));
typedef float f32x4 __attribute__((ext_vector_type(4)));
typedef short bf16x8 __attribute__((ext_vector_type(8)));

#if defined(__has_builtin)
# if __has_builtin(__builtin_amdgcn_exp2f)
#  define EXP2F(x) __builtin_amdgcn_exp2f(x)
# else
#  define EXP2F(x) exp2f(x)
# endif
#else
# define EXP2F(x) exp2f(x)
#endif

__device__ __forceinline__ float gelu_f(float v) {
  return 0.5f * v * (1.0f + erff(v * 0.70710678118654752f));
}

__device__ __forceinline__ unsigned short f2bf(float v) {
  __hip_bfloat16 h = __float2bfloat16(v);
  return *reinterpret_cast<unsigned short*>(&h);
}

// ---------------- K1: in_proj via bf16 MFMA + depthwise conv3 + gelu ------
// cs=0: x-half (conv+gelu -> xxc); cs=1: z-half (gelu -> zg). 80-row padded
// product tile (rows l0-1..l0+78, clamped); 30 MFMA-tiles (5m x 6n, K=96)
// distributed flat over 4 waves, static acc indexing; product overlays the
// bf16 staging post-barrier. Epilogue identical to the proven fp32 version.
__global__ __launch_bounds__(256) void k_front(
    const float* __restrict__ x, const float* __restrict__ w,
    const float* __restrict__ cw,
    float* __restrict__ xxc, float* __restrict__ zg)
{
  __shared__ __align__(16) char smem[80 * 104 * 2 + 96 * 104 * 2];  // 36.6KB
  unsigned short* sxb = reinterpret_cast<unsigned short*>(smem);              // [80][104]
  unsigned short* swb = reinterpret_cast<unsigned short*>(smem + 80 * 104 * 2); // [96][104]
  const int tid = threadIdx.x;
  const int lt = blockIdx.x, cs = blockIdx.y, b = blockIdx.z;
  const int l0 = lt * 64;
  const int lbase = l0 - 1;

  for (int i = tid; i < 80 * 24; i += 256) {
    const int r = i / 24, q = i % 24;
    int l = lbase + r; l = l < 0 ? 0 : (l >= L_ ? L_ - 1 : l);
    const float4 v = reinterpret_cast<const float4*>(x + ((size_t)b * L_ + l) * DM)[q];
    ushort4 u;
    u.x = f2bf(v.x); u.y = f2bf(v.y); u.z = f2bf(v.z); u.w = f2bf(v.w);
    *reinterpret_cast<ushort4*>(&sxb[r * 104 + q * 4]) = u;
  }
  const float* wp = w + (size_t)cs * 96 * DM;
  for (int i = tid; i < 96 * 24; i += 256) {
    const int r = i / 24, q = i % 24;
    const float4 v = reinterpret_cast<const float4*>(wp + (size_t)r * DM)[q];
    ushort4 u;
    u.x = f2bf(v.x); u.y = f2bf(v.y); u.z = f2bf(v.z); u.w = f2bf(v.w);
    *reinterpret_cast<ushort4*>(&swb[r * 104 + q * 4]) = u;
  }
  __syncthreads();

  const int wv = tid >> 6, lane = tid & 63;
  const int lrow = lane & 15, lkg = lane >> 4;
  f32x4 acc[8];
#pragma unroll
  for (int i = 0; i < 8; ++i) {
    acc[i] = (f32x4){0.f, 0.f, 0.f, 0.f};
    const int tile = wv + 4 * i;
    if (tile < 30) {
      const int mt = tile / 6, nt = tile - mt * 6;
#pragma unroll
      for (int kk = 0; kk < 3; ++kk) {
        const int kbase = kk * 32 + lkg * 8;
        const bf16x8 af = *reinterpret_cast<const bf16x8*>(&sxb[(mt * 16 + lrow) * 104 + kbase]);
        const bf16x8 bfm = *reinterpret_cast<const bf16x8*>(&swb[(nt * 16 + lrow) * 104 + kbase]);
        acc[i] = __builtin_amdgcn_mfma_f32_16x16x32_bf16(af, bfm, acc[i], 0, 0, 0);
      }
    }
  }
  __syncthreads();  // all LDS reads complete; safe to overlay

  float* sprod = reinterpret_cast<float*>(smem);  // [80][100] fp32 overlay
#pragma unroll
  for (int i = 0; i < 8; ++i) {
    const int tile = wv + 4 * i;
    if (tile < 30) {
      const int mt = tile / 6, nt = tile - mt * 6;
      const int row = mt * 16 + lkg * 4;
      const int col = nt * 16 + lrow;
#pragma unroll
      for (int reg = 0; reg < 4; ++reg)
        sprod[(row + reg) * 100 + col] = acc[i][reg];
    }
  }
  __syncthreads();

  if (cs == 0) {
    float* op = xxc + ((size_t)b * L_ + l0) * DI;
    for (int i = tid; i < 64 * 24; i += 256) {
      const int ro = i / 24, q = i % 24;
      const int lo = l0 + ro;
      const float4 xm4 = *reinterpret_cast<const float4*>(&sprod[ro * 100 + q * 4]);
      const float4 x04 = *reinterpret_cast<const float4*>(&sprod[(ro + 1) * 100 + q * 4]);
      const float4 xq4 = *reinterpret_cast<const float4*>(&sprod[(ro + 2) * 100 + q * 4]);
      const float mzero = (lo > 0) ? 1.f : 0.f;
      const float qzero = (lo < L_ - 1) ? 1.f : 0.f;
      float4 o;
      {
        const int d0 = q * 4;
        const float* c = cw + d0 * 3;
        o.x = gelu_f(c[0] * xm4.x * mzero + c[1]  * x04.x + c[2]  * xq4.x * qzero);
        o.y = gelu_f(c[3] * xm4.y * mzero + c[4]  * x04.y + c[5]  * xq4.y * qzero);
        o.z = gelu_f(c[6] * xm4.z * mzero + c[7]  * x04.z + c[8]  * xq4.z * qzero);
        o.w = gelu_f(c[9] * xm4.w * mzero + c[10] * x04.w + c[11] * xq4.w * qzero);
      }
      reinterpret_cast<float4*>(op + (size_t)ro * DI)[q] = o;
    }
  } else {
    float* op = zg + ((size_t)b * L_ + l0) * DI;
    for (int i = tid; i < 64 * 24; i += 256) {
      const int ro = i / 24, q = i % 24;
      const float4 v = *reinterpret_cast<const float4*>(&sprod[(ro + 1) * 100 + q * 4]);
      float4 o;
      o.x = gelu_f(v.x); o.y = gelu_f(v.y); o.z = gelu_f(v.z); o.w = gelu_f(v.w);
      reinterpret_cast<float4*>(op + (size_t)ro * DI)[q] = o;
    }
  }
}

// ---------------- K3: x_proj + dt_proj + softplus via bf16 MFMA ----------
__global__ __launch_bounds__(256) void k_xproj(
    const float* __restrict__ xxc, const float* __restrict__ xpw,
    const float* __restrict__ dtw,
    __hip_bfloat16* __restrict__ delta, __hip_bfloat16* __restrict__ Bs,
    __hip_bfloat16* __restrict__ Cs)
{
  __shared__ __align__(16) unsigned short sxb[64][104];  // x tile bf16 (pad 104)
  __shared__ __align__(16) unsigned short swb[144 * 104];// W bf16 [144][104]; reused post-MFMA
  __shared__ __align__(16) float sdtw[576];              // dt_projs_w[k] (96x6)
  const int tid = threadIdx.x;
  const int lt = blockIdx.x, kdir = blockIdx.y, b = blockIdx.z;
  const int l0 = lt * 64;
  const bool rev = (kdir & 1) != 0;

  for (int i = tid; i < 576; i += 256) sdtw[i] = dtw[(size_t)kdir * 576 + i];

  for (int i = tid; i < 64 * 24; i += 256) {
    const int r = i / 24, q = i % 24;
    const int l = l0 + r;
    const int p = rev ? (L_ - 1 - l) : l;
    const float4 v = reinterpret_cast<const float4*>(xxc + ((size_t)b * L_ + p) * DI)[q];
    ushort4 u;
    u.x = f2bf(v.x); u.y = f2bf(v.y); u.z = f2bf(v.z); u.w = f2bf(v.w);
    *reinterpret_cast<ushort4*>(&sxb[r][q * 4]) = u;
  }
  const float* wp = xpw + (size_t)kdir * CDIM * DI;
  for (int i = tid; i < 144 * 24; i += 256) {
    const int r = i / 24, q = i % 24;
    float4 v = make_float4(0.f, 0.f, 0.f, 0.f);
    if (r < CDIM) v = reinterpret_cast<const float4*>(wp + (size_t)r * DI)[q];
    ushort4 u;
    u.x = f2bf(v.x); u.y = f2bf(v.y); u.z = f2bf(v.z); u.w = f2bf(v.w);
    *reinterpret_cast<ushort4*>(&swb[r * 104 + q * 4]) = u;
  }
  __syncthreads();

  const int wv = tid >> 6, lane = tid & 63;
  const int m0 = wv * 16;
  const int lrow = lane & 15, lkg = lane >> 4;
  f32x4 acc[9];
#pragma unroll
  for (int n = 0; n < 9; ++n) acc[n] = (f32x4){0.f, 0.f, 0.f, 0.f};

#pragma unroll
  for (int kk = 0; kk < 3; ++kk) {
    const int kbase = kk * 32 + lkg * 8;
    const bf16x8 af = *reinterpret_cast<const bf16x8*>(&sxb[m0 + lrow][kbase]);
#pragma unroll
    for (int n = 0; n < 9; ++n) {
      const bf16x8 bfm = *reinterpret_cast<const bf16x8*>(&swb[(n * 16 + lrow) * 104 + kbase]);
      acc[n] = __builtin_amdgcn_mfma_f32_16x16x32_bf16(af, bfm, acc[n], 0, 0, 0);
    }
  }
  __syncthreads();

  unsigned short* soB = swb;               // [64][68] bf16
  unsigned short* soC = swb + 64 * 68;     // [64][68] bf16
  float* sdts = reinterpret_cast<float*>(swb + 2 * 64 * 68);  // [64][8] fp32

  {
    const int row = m0 + lkg * 4;
#pragma unroll
    for (int n = 0; n < 9; ++n) {
      const int c = n * 16 + lrow;
#pragma unroll
      for (int reg = 0; reg < 4; ++reg) {
        const float v = acc[n][reg];
        const int rr = row + reg;
        if (c < RK)            sdts[rr * 8 + c] = v;
        else if (c < RK + NS)  soB[rr * 68 + (c - RK)] = f2bf(v);
        else if (c < CDIM)     soC[rr * 68 + (c - RK - NS)] = f2bf(v);
      }
    }
  }
  __syncthreads();

  const size_t bk = (size_t)(b * KG_ + kdir);
  {
    unsigned short* bsg = reinterpret_cast<unsigned short*>(Bs);
    unsigned short* csg = reinterpret_cast<unsigned short*>(Cs);
    const size_t nbase = (bk * L_ + l0) * NS;
    for (int i = tid; i < 64 * 16; i += 256) {
      const int r = i >> 4, q = i & 15;
      const ushort4 vb = *reinterpret_cast<const ushort4*>(&soB[r * 68 + q * 4]);
      const ushort4 vc = *reinterpret_cast<const ushort4*>(&soC[r * 68 + q * 4]);
      *reinterpret_cast<ushort4*>(bsg + nbase + (size_t)r * NS + q * 4) = vb;
      *reinterpret_cast<ushort4*>(csg + nbase + (size_t)r * NS + q * 4) = vc;
    }
  }
  {
    unsigned short* dg = reinterpret_cast<unsigned short*>(delta);
    const size_t dbase = (bk * L_ + l0) * DI;
    for (int i = tid; i < 64 * 24; i += 256) {
      const int r = i / 24, q = i - r * 24;
      const int dc0 = q * 4;
      ushort4 u;
      float o[4];
#pragma unroll
      for (int e = 0; e < 4; ++e) {
        const int dc = dc0 + e;
        float s = 0.f;
#pragma unroll
        for (int rr6 = 0; rr6 < RK; ++rr6)
          s += sdts[r * 8 + rr6] * sdtw[dc * RK + rr6];
        o[e] = (s > 20.f) ? s : log1pf(__expf(s));
      }
      u.x = f2bf(o[0]); u.y = f2bf(o[1]); u.z = f2bf(o[2]); u.w = f2bf(o[3]);
      *reinterpret_cast<ushort4*>(dg + dbase + (size_t)r * DI + dc0) = u;
    }
  }
}

// ---------------- K4: chunked selective scan (R6 code, verbatim) ----------
__global__ __launch_bounds__(768) void k_scan(
    const float* __restrict__ xxc,
    const __hip_bfloat16* __restrict__ delta,
    const __hip_bfloat16* __restrict__ Bs,
    const __hip_bfloat16* __restrict__ Cs,
    const float* __restrict__ A_logs, const float* __restrict__ Ds,
    float* __restrict__ ysum)
{
  __shared__ __align__(16) float s_du[STG][192];  // interleaved (delta, delta*u)
  __shared__ __align__(16) float s_u[STG][96];
  __shared__ __align__(16) float s_B[STG][64];
  __shared__ __align__(16) float s_C[STG][64];
  __shared__ __align__(16) float s_y[STG][96];
  const int tid = threadIdx.x;
  const int ci = blockIdx.x, k = blockIdx.y, b = blockIdx.z;
  const int d = tid >> 3, j = tid & 7;
  const int jn = j * 8;
  const bool rev = (k & 1) != 0;
  const float LOG2E = 1.4426950408889634f;

  const int r96 = tid / 96;
  const int c96 = tid - r96 * 96;
  const int r64 = tid >> 6;
  const int c64 = tid & 63;

  f32x2 a2[4], h[4];
#pragma unroll
  for (int p = 0; p < 4; ++p) {
    const int n = jn + 2 * p;
    a2[p].x = -__expf(A_logs[((size_t)(k * DI + d)) * NS + n])     * LOG2E;
    a2[p].y = -__expf(A_logs[((size_t)(k * DI + d)) * NS + n + 1]) * LOG2E;
    h[p].x = 0.f; h[p].y = 0.f;
  }
  const float Dc = Ds[k * DI + c96];

  const int emit0 = ci * CL;
  const int lstart = (emit0 - NWARM > 0) ? (emit0 - NWARM) : 0;
  const int lend = emit0 + CL;
  const size_t bk = (size_t)(b * KG_ + k);

  for (int s = lstart; s < lend; s += STG) {
    __syncthreads();
    {
      const size_t dbase = (bk * L_ + s) * DI;
      const int pbase = rev ? (L_ - 1 - s) : s;
      const int psgn  = rev ? -1 : 1;
      const float* ubase = xxc + ((size_t)b * L_ + pbase) * DI + c96;
#pragma unroll
      for (int it = 0; it < 4; ++it) {
        const int t = r96 + 8 * it;
        const float dl = __bfloat162float(delta[dbase + (size_t)t * DI + c96]);
        const float uu = ubase[(ptrdiff_t)psgn * t * DI];
        f32x2 v; v.x = dl; v.y = dl * uu;
        *(f32x2*)&s_du[t][2 * c96] = v;
        s_u[t][c96] = uu;
      }
      const size_t nbase = (bk * L_ + s) * NS;
#pragma unroll
      for (int it = 0; it < 3; ++it) {
        const int t = r64 + 12 * it;
        if (t < STG) {
          s_B[t][c64] = __bfloat162float(Bs[nbase + (size_t)t * NS + c64]);
          s_C[t][c64] = __bfloat162float(Cs[nbase + (size_t)t * NS + c64]);
        }
      }
    }
    __syncthreads();
    const bool emit = (s >= emit0);
#pragma unroll 8
    for (int t = 0; t < STG; ++t) {
      const f32x2 du = *(const f32x2*)&s_du[t][2 * d];
      const float dlt = du.x, bu = du.y;
      const f32x2 dlt2 = {dlt, dlt};
      const f32x2 bu2 = {bu, bu};
      const f32x4 Bv0 = *(const f32x4*)&s_B[t][jn];
      const f32x4 Bv1 = *(const f32x4*)&s_B[t][jn + 4];
      const f32x4 Cv0 = *(const f32x4*)&s_C[t][jn];
      const f32x4 Cv1 = *(const f32x4*)&s_C[t][jn + 4];
      const f32x2 bp[4] = {{Bv0.x, Bv0.y}, {Bv0.z, Bv0.w},
                           {Bv1.x, Bv1.y}, {Bv1.z, Bv1.w}};
      const f32x2 cp[4] = {{Cv0.x, Cv0.y}, {Cv0.z, Cv0.w},
                           {Cv1.x, Cv1.y}, {Cv1.z, Cv1.w}};
      f32x2 y2 = {0.f, 0.f};
#pragma unroll
      for (int p = 0; p < 4; ++p) {
        const f32x2 arg = dlt2 * a2[p];
        f32x2 e;
        e.x = EXP2F(arg.x);
        e.y = EXP2F(arg.y);
        h[p] = e * h[p] + bu2 * bp[p];
        y2 += h[p] * cp[p];
      }
      float y = y2.x + y2.y;
      y += __shfl_xor(y, 1);
      y += __shfl_xor(y, 2);
      y += __shfl_xor(y, 4);
      if (emit && j == 0) s_y[t][d] = y;
    }
    if (emit) {
      __syncthreads();
      const int pbase = rev ? (L_ - 1 - s) : s;
      const int psgn  = rev ? -1 : 1;
      float* ybase = ysum + ((size_t)b * L_ + pbase) * DI + c96;
#pragma unroll
      for (int it = 0; it < 4; ++it) {
        const int t = r96 + 8 * it;
        atomicAdd(ybase + (ptrdiff_t)psgn * t * DI,
                  fmaf(Dc, s_u[t][c96], s_y[t][c96]));
      }
    }
  }
}

// ---------------- K5: out = (ysum .* zg) @ Wout^T via bf16 MFMA ----------
__global__ __launch_bounds__(256) void k_out(
    const float* __restrict__ ysum, const float* __restrict__ zg,
    const float* __restrict__ wout, float* __restrict__ out)
{
  __shared__ __align__(16) char smem[64 * 104 * 2 + 96 * 104 * 2];
  unsigned short* sab = reinterpret_cast<unsigned short*>(smem);             // [64][104]
  unsigned short* swb = reinterpret_cast<unsigned short*>(smem + 64*104*2);  // [96][104]
  const int tid = threadIdx.x;
  const int lt = blockIdx.x, b = blockIdx.y;
  const int l0 = lt * 64;
  const size_t rbase = ((size_t)b * L_ + l0) * DI;

  for (int i = tid; i < 64 * 24; i += 256) {
    const int r = i / 24, q = i % 24;
    float4 av = reinterpret_cast<const float4*>(ysum + rbase + (size_t)r * DI)[q];
    const float4 zv = reinterpret_cast<const float4*>(zg + rbase + (size_t)r * DI)[q];
    ushort4 u;
    u.x = f2bf(av.x * zv.x); u.y = f2bf(av.y * zv.y);
    u.z = f2bf(av.z * zv.z); u.w = f2bf(av.w * zv.w);
    *reinterpret_cast<ushort4*>(&sab[r * 104 + q * 4]) = u;
  }
  for (int i = tid; i < 96 * 24; i += 256) {
    const int r = i / 24, q = i % 24;
    const float4 v = reinterpret_cast<const float4*>(wout + (size_t)r * DM)[q];
    ushort4 u;
    u.x = f2bf(v.x); u.y = f2bf(v.y); u.z = f2bf(v.z); u.w = f2bf(v.w);
    *reinterpret_cast<ushort4*>(&swb[r * 104 + q * 4]) = u;
  }
  __syncthreads();

  const int wv = tid >> 6, lane = tid & 63;
  const int m0 = wv * 16;
  const int lrow = lane & 15, lkg = lane >> 4;
  f32x4 acc[6];
#pragma unroll
  for (int n = 0; n < 6; ++n) acc[n] = (f32x4){0.f, 0.f, 0.f, 0.f};

#pragma unroll
  for (int kk = 0; kk < 3; ++kk) {
    const int kbase = kk * 32 + lkg * 8;
    const bf16x8 af = *reinterpret_cast<const bf16x8*>(&sab[(m0 + lrow) * 104 + kbase]);
#pragma unroll
    for (int n = 0; n < 6; ++n) {
      const bf16x8 bfm = *reinterpret_cast<const bf16x8*>(&swb[(n * 16 + lrow) * 104 + kbase]);
      acc[n] = __builtin_amdgcn_mfma_f32_16x16x32_bf16(af, bfm, acc[n], 0, 0, 0);
    }
  }
  __syncthreads();

  float* sout = reinterpret_cast<float*>(smem);  // [64][100] overlay
  {
    const int row = m0 + lkg * 4;
#pragma unroll
    for (int n = 0; n < 6; ++n) {
      const int c = n * 16 + lrow;
#pragma unroll
      for (int reg = 0; reg < 4; ++reg)
        sout[(row + reg) * 100 + c] = acc[n][reg];
    }
  }
  __syncthreads();

  float* op = out + ((size_t)b * L_ + l0) * DM;
  for (int i = tid; i < 64 * 24; i += 256) {
    const int r = i / 24, q = i % 24;
    const float4 v = *reinterpret_cast<const float4*>(&sout[r * 100 + q * 4]);
    reinterpret_cast<float4*>(op + (size_t)r * DM)[q] = v;
  }
}

extern "C" void kernel_launch(void* const* d_in, const int* in_sizes, int n_in,
                              void* d_out, int out_size, void* d_ws, size_t ws_size,
                              hipStream_t stream)
{
  const float* x    = (const float*)d_in[0];
  const float* ipw  = (const float*)d_in[1];
  const float* cw   = (const float*)d_in[2];
  const float* xpw  = (const float*)d_in[3];
  const float* dtw  = (const float*)d_in[4];
  const float* opw  = (const float*)d_in[5];
  const float* alog = (const float*)d_in[6];
  const float* dsv  = (const float*)d_in[7];
  float* out = (float*)d_out;
  char* ws = (char*)d_ws;

  const size_t SZ_XZ  = (size_t)B_ * L_ * 192 * 4;      // region reserved (delta lives here)
  const size_t SZ_F   = (size_t)B_ * L_ * DI * 4;       // 25,165,824
  const size_t SZ_NBF = (size_t)B_ * KG_ * L_ * NS * 2; // 33,554,432

  __hip_bfloat16* dlt  = (__hip_bfloat16*)ws;
  float* xxc           = (float*)(ws + SZ_XZ);
  float* zgp           = (float*)(ws + SZ_XZ + SZ_F);
  __hip_bfloat16* Bsp  = (__hip_bfloat16*)(ws + SZ_XZ + 2 * SZ_F);
  __hip_bfloat16* Csp  = (__hip_bfloat16*)(ws + SZ_XZ + 2 * SZ_F + SZ_NBF);
  float* ysum          = (float*)(ws + SZ_XZ + 2 * SZ_F + 2 * SZ_NBF);

  hipMemsetAsync(ysum, 0, SZ_F, stream);
  k_front  <<<dim3(L_ / 64, 2, B_),   256, 0, stream>>>(x, ipw, cw, xxc, zgp);
  k_xproj  <<<dim3(L_ / 64, KG_, B_), 256, 0, stream>>>(xxc, xpw, dtw, dlt, Bsp, Csp);
  k_scan   <<<dim3(NC, KG_, B_),      768, 0, stream>>>(xxc, dlt, Bsp, Csp, alog, dsv, ysum);
  k_out    <<<dim3(L_ / 64, B_),      256, 0, stream>>>(ysum, zgp, opw, out);
}